// Round 1
// baseline (679.854 us; speedup 1.0000x reference)
//
#include <hip/hip_runtime.h>

#define HW 9216
#define IMG 96
#define CCH 256
#define NCO 45

// ---------------- guidance conv: 3x3, 256 -> 45, padding 1 ----------------
// Partial sums over ci-chunks of 32 (8 chunks) for occupancy.
// grid: (72 spatial tiles [n x 6 x 6 of 16x16], 8 chunks), block 256
__global__ __launch_bounds__(256) void guid_conv(const float* __restrict__ x,
                                                 const float* __restrict__ Wc,
                                                 float* __restrict__ gpart) {
  int tile = blockIdx.x;   // 0..71
  int cc = blockIdx.y;     // 0..7
  int n = tile / 36;
  int tl = tile % 36;
  int th = (tl / 6) * 16, tw = (tl % 6) * 16;
  int t = threadIdx.x;
  int ly = t >> 4, lx = t & 15;
  int h = th + ly, w = tw + lx;

  __shared__ float xs[18 * 18];
  __shared__ float wt[9][48];   // transposed weights [tap][co], padded to 48

  float4 acc4[12];
#pragma unroll
  for (int q = 0; q < 12; ++q) acc4[q] = make_float4(0.f, 0.f, 0.f, 0.f);

  if (t < 27) { int j = t / 3; wt[j][45 + t % 3] = 0.f; }  // zero pad lanes once

  int ci0 = cc * 32;
  for (int ci = ci0; ci < ci0 + 32; ++ci) {
    const float* xp = x + (size_t)(n * CCH + ci) * HW;
    for (int u = t; u < 324; u += 256) {
      int r = u / 18, c = u % 18;
      int gh = th - 1 + r, gw = tw - 1 + c;
      float v = 0.f;
      if (gh >= 0 && gh < 96 && gw >= 0 && gw < 96) v = xp[gh * 96 + gw];
      xs[u] = v;
    }
    const float* wp = Wc + (size_t)ci * 9;
    for (int u = t; u < 405; u += 256) {
      int co = u / 9, j = u % 9;
      wt[j][co] = wp[co * 2304 + j];
    }
    __syncthreads();

    float xv[9];
#pragma unroll
    for (int ky = 0; ky < 3; ++ky)
#pragma unroll
      for (int kx = 0; kx < 3; ++kx)
        xv[ky * 3 + kx] = xs[(ly + ky) * 18 + (lx + kx)];

#pragma unroll
    for (int j = 0; j < 9; ++j) {
      float s = xv[j];
      const float4* w4 = reinterpret_cast<const float4*>(&wt[j][0]);
#pragma unroll
      for (int q = 0; q < 12; ++q) {
        float4 wv = w4[q];
        acc4[q].x += wv.x * s;
        acc4[q].y += wv.y * s;
        acc4[q].z += wv.z * s;
        acc4[q].w += wv.w * s;
      }
    }
    __syncthreads();
  }

  const float* accs = reinterpret_cast<const float*>(acc4);
  int p = h * 96 + w;
  float* gp = gpart + (size_t)(cc * 2 + n) * NCO * HW + p;
#pragma unroll
  for (int co = 0; co < NCO; ++co) gp[(size_t)co * HW] = accs[co];
}

// ---------------- sum 8 partials + grouped softmax (5 groups of 9) ----------------
// grid 72, block 256 (one thread per (n,p))
__global__ __launch_bounds__(256) void softmax45(const float* __restrict__ gpart,
                                                 float* __restrict__ gsm) {
  int gid = blockIdx.x * 256 + threadIdx.x;  // 0..18431
  int n = gid / HW, p = gid % HW;
  float g[45];
#pragma unroll
  for (int co = 0; co < 45; ++co) g[co] = 0.f;
  for (int ccI = 0; ccI < 8; ++ccI) {
    const float* gp = gpart + (size_t)(ccI * 2 + n) * NCO * HW + p;
#pragma unroll
    for (int co = 0; co < 45; ++co) g[co] += gp[(size_t)co * HW];
  }
  for (int grp = 0; grp < 5; ++grp) {
    float m = -1e30f;
#pragma unroll
    for (int k = 0; k < 9; ++k) m = fmaxf(m, g[grp * 9 + k]);
    float e[9];
    float s = 0.f;
#pragma unroll
    for (int k = 0; k < 9; ++k) {
      e[k] = __expf(g[grp * 9 + k] - m);
      s += e[k];
    }
    float inv = 1.f / s;
#pragma unroll
    for (int k = 0; k < 9; ++k)
      gsm[(size_t)(n * 45 + grp * 9 + k) * HW + p] = e[k] * inv;
  }
}

// ---------------- z_b = Ws[:, 256b:256b+256] . x   (output channel-last) ----------------
// out[n][p][co], tiles 64(p) x 64(co), K=256 in steps of 32. grid (144,4,2), block 256.
__global__ __launch_bounds__(256) void gemm_z(const float* __restrict__ x,
                                              const float* __restrict__ Ws,
                                              float* __restrict__ out, int bsel) {
  __shared__ float As[32][64];   // As[kk][mm] = x[ci0+kk][p0+mm]
  __shared__ float Bs[32][68];   // Bs[kk][nn] = Ws[co0+nn][bsel*256+ci0+kk]
  int t = threadIdx.x;
  int p0 = blockIdx.x * 64, co0 = blockIdx.y * 64, n = blockIdx.z;
  const float* xb = x + (size_t)n * CCH * HW;
  const float* wb = Ws + (size_t)bsel * CCH;
  float acc[4][4] = {{0.f}};

  for (int k0 = 0; k0 < 256; k0 += 32) {
#pragma unroll
    for (int r = 0; r < 8; ++r) {
      int u = t + r * 256;
      int mm = u & 63, kk = u >> 6;
      As[kk][mm] = xb[(size_t)(k0 + kk) * HW + p0 + mm];
    }
#pragma unroll
    for (int r = 0; r < 8; ++r) {
      int u = t + r * 256;
      int kk = u & 31, nn = u >> 5;
      Bs[kk][nn] = wb[(size_t)(co0 + nn) * 1536 + k0 + kk];
    }
    __syncthreads();
    int mm0 = (t >> 4) << 2;
    int nn0 = (t & 15) << 2;
#pragma unroll
    for (int kk = 0; kk < 32; ++kk) {
      float4 av = *reinterpret_cast<const float4*>(&As[kk][mm0]);
      float4 bv = *reinterpret_cast<const float4*>(&Bs[kk][nn0]);
      acc[0][0] += av.x * bv.x; acc[0][1] += av.x * bv.y; acc[0][2] += av.x * bv.z; acc[0][3] += av.x * bv.w;
      acc[1][0] += av.y * bv.x; acc[1][1] += av.y * bv.y; acc[1][2] += av.y * bv.z; acc[1][3] += av.y * bv.w;
      acc[2][0] += av.z * bv.x; acc[2][1] += av.z * bv.y; acc[2][2] += av.z * bv.z; acc[2][3] += av.z * bv.w;
      acc[3][0] += av.w * bv.x; acc[3][1] += av.w * bv.y; acc[3][2] += av.w * bv.z; acc[3][3] += av.w * bv.w;
    }
    __syncthreads();
  }

  float* ob = out + (size_t)n * HW * CCH;
  int mm0 = (t >> 4) << 2;
  int nn0 = (t & 15) << 2;
#pragma unroll
  for (int i = 0; i < 4; ++i) {
    float4 v = make_float4(acc[i][0], acc[i][1], acc[i][2], acc[i][3]);
    *reinterpret_cast<float4*>(&ob[(size_t)(p0 + mm0 + i) * CCH + co0 + nn0]) = v;
  }
}

// ---------------- yacc += sum_k g_k . shift_k(z)  (one branch) ----------------
// grid (9216, 2), block 256 (= co). g loads are block-uniform -> scalar path.
__global__ __launch_bounds__(256) void accum(const float* __restrict__ z,
                                             const float* __restrict__ gsm,
                                             float* __restrict__ yacc, int gbase, int d) {
  int p = blockIdx.x, n = blockIdx.y, t = threadIdx.x;
  int h = p / 96, w = p % 96;
  size_t base = (size_t)n * HW * CCH;
  float y = yacc[base + (size_t)p * CCH + t];
#pragma unroll
  for (int k = 0; k < 9; ++k) {
    int dy = (k / 3 - 1) * d, dx = (k % 3 - 1) * d;
    int hh = h + dy, ww = w + dx;
    if (hh >= 0 && hh < 96 && ww >= 0 && ww < 96) {
      float gk = gsm[(size_t)(n * 45 + gbase + k) * HW + p];
      y += gk * z[base + (size_t)(hh * 96 + ww) * CCH + t];
    }
  }
  yacc[base + (size_t)p * CCH + t] = y;
}

// ---------------- batch-norm stats: per-co sum / sumsq over 18432 (n,p) ----------------
// grid 144, block 256 (= co); each block covers 128 (n,p) rows; atomic accumulate.
__global__ __launch_bounds__(256) void bn_stats(const float* __restrict__ yacc,
                                                float* __restrict__ stats) {
  int t = threadIdx.x;
  float s = 0.f, s2 = 0.f;
  size_t base = (size_t)blockIdx.x * 128 * CCH + t;
  for (int i = 0; i < 128; ++i) {
    float v = yacc[base + (size_t)i * CCH];
    s += v;
    s2 += v * v;
  }
  atomicAdd(&stats[t], s);
  atomicAdd(&stats[256 + t], s2);
}

// ---------------- normalize + affine + transpose [n][p][co] -> [n][co][p] ----------------
// grid (144,4,2), block 256; 64x64 tile via LDS.
__global__ __launch_bounds__(256) void bn_apply(const float* __restrict__ yacc,
                                                const float* __restrict__ stats,
                                                const float* __restrict__ gamma,
                                                const float* __restrict__ beta,
                                                float* __restrict__ out) {
  __shared__ float tile[64][65];
  int t = threadIdx.x;
  int p0 = blockIdx.x * 64, co0 = blockIdx.y * 64, n = blockIdx.z;
  int cl = t & 63, q = t >> 6;
#pragma unroll
  for (int i = 0; i < 16; ++i) {
    int pr = q + i * 4;
    tile[pr][cl] = yacc[((size_t)n * HW + p0 + pr) * CCH + co0 + cl];
  }
  __syncthreads();
  const float inv_cnt = 1.f / 18432.f;
#pragma unroll
  for (int i = 0; i < 16; ++i) {
    int cr = q + i * 4;
    int c = co0 + cr;
    float mean = stats[c] * inv_cnt;
    float var = stats[256 + c] * inv_cnt - mean * mean;
    float sc = rsqrtf(var + 1e-5f) * gamma[c];
    float sh = beta[c] - mean * sc;
    out[(size_t)(n * CCH + c) * HW + p0 + cl] = tile[cl][cr] * sc + sh;
  }
}

extern "C" void kernel_launch(void* const* d_in, const int* in_sizes, int n_in,
                              void* d_out, int out_size, void* d_ws, size_t ws_size,
                              hipStream_t stream) {
  const float* x = (const float*)d_in[0];      // [2][256][96][96]
  const float* Wc = (const float*)d_in[1];     // [45][256][3][3]
  const float* Ws = (const float*)d_in[2];     // [256][1536]
  const float* gamma = (const float*)d_in[3];  // [256]
  const float* beta = (const float*)d_in[4];   // [256]
  float* out = (float*)d_out;                  // [2][256][96][96]

  float* ws = (float*)d_ws;
  float* gpart = ws;                                   // 8*2*45*9216
  float* gsm = gpart + (size_t)8 * 2 * 45 * HW;        // 2*45*9216
  float* z = gsm + (size_t)2 * 45 * HW;                // 2*9216*256
  float* yacc = z + (size_t)2 * HW * CCH;              // 2*9216*256
  float* stats = yacc + (size_t)2 * HW * CCH;          // 512

  hipMemsetAsync(stats, 0, 512 * sizeof(float), stream);
  guid_conv<<<dim3(72, 8), 256, 0, stream>>>(x, Wc, gpart);
  softmax45<<<72, 256, 0, stream>>>(gpart, gsm);
  // b = 0: plain 1x1 of x, write straight into the accumulator
  gemm_z<<<dim3(144, 4, 2), 256, 0, stream>>>(x, Ws, yacc, 0);
  const int dil[5] = {1, 6, 12, 24, 36};
  for (int b = 1; b <= 5; ++b) {
    gemm_z<<<dim3(144, 4, 2), 256, 0, stream>>>(x, Ws, z, b);
    accum<<<dim3(9216, 2), 256, 0, stream>>>(z, gsm, yacc, 9 * (b - 1), dil[b - 1]);
  }
  bn_stats<<<144, 256, 0, stream>>>(yacc, stats);
  bn_apply<<<dim3(144, 4, 2), 256, 0, stream>>>(yacc, stats, gamma, beta, out);
}

// Round 2
// 663.629 us; speedup vs baseline: 1.0244x; 1.0244x over previous
//
#include <hip/hip_runtime.h>

typedef __bf16 bf16x8 __attribute__((ext_vector_type(8)));
typedef float f32x4 __attribute__((ext_vector_type(4)));

#define HW 9216
#define CCH 256

__device__ __forceinline__ unsigned short f2bf(float f) {
  unsigned u = __float_as_uint(f);
  unsigned r = (u + 0x7FFFu + ((u >> 16) & 1u)) >> 16;
  return (unsigned short)r;
}
__device__ __forceinline__ float bf2f(unsigned short h) {
  return __uint_as_float(((unsigned)h) << 16);
}

// ---------- x [n][ci][p] fp32 -> xb [n*9216+p][ci] bf16 (LDS tile transpose) ----------
__global__ __launch_bounds__(256) void xpose(const float* __restrict__ x,
                                             unsigned short* __restrict__ xb) {
  __shared__ float tile[64][65];
  int t = threadIdx.x;
  int p0 = blockIdx.x * 64, ci0 = blockIdx.y * 64, n = blockIdx.z;
  int cl = t & 63, q = t >> 6;
#pragma unroll
  for (int i = 0; i < 16; ++i) {
    int cir = q + i * 4;
    tile[cir][cl] = x[((size_t)(n * 256 + ci0 + cir)) * HW + p0 + cl];
  }
  __syncthreads();
#pragma unroll
  for (int i = 0; i < 16; ++i) {
    int pr = q + i * 4;
    xb[((size_t)(n * HW + p0 + pr)) * 256 + ci0 + cl] = f2bf(tile[cl][pr]);
  }
}

// ---------- weight repack: Wsb[j=b*256+co][k=ci] bf16 ; Wcb[co48][k=j*256+ci] bf16 ----------
__global__ __launch_bounds__(256) void prep_w(const float* __restrict__ Ws,
                                              const float* __restrict__ Wc,
                                              unsigned short* __restrict__ Wsb,
                                              unsigned short* __restrict__ Wcb) {
  int u = blockIdx.x * 256 + threadIdx.x;
  if (u < 393216) {
    int j = u >> 8, k = u & 255;
    int co = j & 255, b = j >> 8;
    Wsb[u] = f2bf(Ws[(size_t)co * 1536 + b * 256 + k]);
  } else {
    int v = u - 393216;
    if (v < 110592) {
      int co = v / 2304, r = v % 2304;
      int j = r >> 8, ci = r & 255;
      Wcb[v] = (co < 45) ? f2bf(Wc[(size_t)co * 2304 + ci * 9 + j]) : (unsigned short)0;
    }
  }
}

// ---------- z[m][zc0..zc0+128) = xb . Wsb^T  (MFMA, 128x128 tile, BK=32) ----------
__global__ __launch_bounds__(256) void gemm_z(const unsigned short* __restrict__ xb,
                                              const unsigned short* __restrict__ Wsb,
                                              unsigned short* __restrict__ z, int jbase) {
  __shared__ unsigned short As[4 * 128 * 8];  // [q][mm][j]
  __shared__ unsigned short Bs[4 * 128 * 8];  // [q][nn][j]
  int t = threadIdx.x;
  int m0 = blockIdx.x * 128;
  int jr0 = jbase + blockIdx.y * 128;  // row in Wsb
  int zc0 = blockIdx.y * 128;          // col in z (768-wide local)
  int wid = t >> 6, lane = t & 63;
  int wm = (wid >> 1) * 64, wn = (wid & 1) * 64;
  int q = lane >> 4, ln = lane & 15;
  f32x4 acc[4][4] = {};

  for (int k0 = 0; k0 < 256; k0 += 32) {
#pragma unroll
    for (int r = 0; r < 2; ++r) {
      int idx = t + r * 256;
      int mm = idx >> 2, kq = idx & 3;
      ((uint4*)As)[kq * 128 + mm] =
          *(const uint4*)(xb + (size_t)(m0 + mm) * 256 + k0 + kq * 8);
      ((uint4*)Bs)[kq * 128 + mm] =
          *(const uint4*)(Wsb + (size_t)(jr0 + mm) * 256 + k0 + kq * 8);
    }
    __syncthreads();
    bf16x8 a[4], b[4];
#pragma unroll
    for (int f = 0; f < 4; ++f) {
      a[f] = ((const bf16x8*)As)[q * 128 + wm + f * 16 + ln];
      b[f] = ((const bf16x8*)Bs)[q * 128 + wn + f * 16 + ln];
    }
#pragma unroll
    for (int fm = 0; fm < 4; ++fm)
#pragma unroll
      for (int fn = 0; fn < 4; ++fn)
        acc[fm][fn] = __builtin_amdgcn_mfma_f32_16x16x32_bf16(a[fm], b[fn], acc[fm][fn], 0, 0, 0);
    __syncthreads();
  }

#pragma unroll
  for (int fm = 0; fm < 4; ++fm) {
    int mrow = m0 + wm + fm * 16 + q * 4;
#pragma unroll
    for (int fn = 0; fn < 4; ++fn) {
      int col = zc0 + wn + fn * 16 + ln;
#pragma unroll
      for (int r = 0; r < 4; ++r)
        z[(size_t)(mrow + r) * 768 + col] = f2bf(acc[fm][fn][r]);
    }
  }
}

// ---------- guidance: g45[m][48] = sum_j shift_j(xb) . Wcb^T  (K=2304, BM=64, BN=48) ----------
__global__ __launch_bounds__(256) void gemm_g(const unsigned short* __restrict__ xb,
                                              const unsigned short* __restrict__ Wcb,
                                              float* __restrict__ g45) {
  __shared__ unsigned short As[4 * 64 * 8];
  __shared__ unsigned short Bs[4 * 48 * 8];
  int t = threadIdx.x;
  int m0 = blockIdx.x * 64;
  int wid = t >> 6, lane = t & 63;
  int q = lane >> 4, ln = lane & 15;
  int mm = t >> 2, kq = t & 3;
  int m = m0 + mm;
  int nimg = m / HW, p = m % HW;
  int h = p / 96, w = p % 96;
  int mbase = nimg * HW;
  f32x4 acc[3] = {};

  for (int k0 = 0; k0 < 2304; k0 += 32) {
    int j = k0 >> 8;
    int dy = j / 3 - 1, dx = j % 3 - 1;
    int hh = h + dy, ww = w + dx;
    uint4 av = make_uint4(0, 0, 0, 0);
    if ((unsigned)hh < 96u && (unsigned)ww < 96u)
      av = *(const uint4*)(xb + (size_t)(mbase + hh * 96 + ww) * 256 + (k0 & 255) + kq * 8);
    ((uint4*)As)[kq * 64 + mm] = av;
    if (t < 192) {
      int nn = t >> 2, kq2 = t & 3;
      ((uint4*)Bs)[kq2 * 48 + nn] = *(const uint4*)(Wcb + (size_t)nn * 2304 + k0 + kq2 * 8);
    }
    __syncthreads();
    bf16x8 a = ((const bf16x8*)As)[q * 64 + wid * 16 + ln];
#pragma unroll
    for (int fn = 0; fn < 3; ++fn) {
      bf16x8 b = ((const bf16x8*)Bs)[q * 48 + fn * 16 + ln];
      acc[fn] = __builtin_amdgcn_mfma_f32_16x16x32_bf16(a, b, acc[fn], 0, 0, 0);
    }
    __syncthreads();
  }
#pragma unroll
  for (int fn = 0; fn < 3; ++fn) {
    int col = fn * 16 + ln;
    int mrow = m0 + wid * 16 + q * 4;
#pragma unroll
    for (int r = 0; r < 4; ++r)
      g45[(size_t)(mrow + r) * 48 + col] = acc[fn][r];
  }
}

// ---------- grouped softmax over 5 groups of 9 ----------
__global__ __launch_bounds__(256) void softmax45(const float* __restrict__ g45,
                                                 float* __restrict__ gsm) {
  int m = blockIdx.x * 256 + threadIdx.x;
  const float* g = g45 + (size_t)m * 48;
  float* o = gsm + (size_t)m * 48;
  for (int grp = 0; grp < 5; ++grp) {
    float v[9], mx = -1e30f;
#pragma unroll
    for (int k = 0; k < 9; ++k) { v[k] = g[grp * 9 + k]; mx = fmaxf(mx, v[k]); }
    float s = 0.f;
#pragma unroll
    for (int k = 0; k < 9; ++k) { v[k] = __expf(v[k] - mx); s += v[k]; }
    float inv = 1.f / s;
#pragma unroll
    for (int k = 0; k < 9; ++k) o[grp * 9 + k] = v[k] * inv;
  }
}

// ---------- fused branch accumulation (3 branches/pass) + BN stats on final pass ----------
__global__ __launch_bounds__(256) void accum(const unsigned short* __restrict__ z,
                                             const float* __restrict__ gsm,
                                             float* __restrict__ yacc,
                                             float* __restrict__ stats, int bstart) {
  int t = threadIdx.x;
  int m0 = blockIdx.x * 72;
  const int dil[6] = {0, 1, 6, 12, 24, 36};
  float s = 0.f, s2 = 0.f;
  for (int mi = 0; mi < 72; ++mi) {
    int m = m0 + mi;
    int p = m % HW;
    int h = p / 96, w = p % 96;
    float y = bstart ? yacc[(size_t)m * 256 + t] : 0.f;
#pragma unroll
    for (int bl = 0; bl < 3; ++bl) {
      int b = bstart + bl;
      if (b == 0) {
        y += bf2f(z[(size_t)m * 768 + t]);
      } else {
        int d = dil[b];
        const float* gr = gsm + (size_t)m * 48 + (b - 1) * 9;
#pragma unroll
        for (int k = 0; k < 9; ++k) {
          int dy = (k / 3 - 1) * d, dx = (k % 3 - 1) * d;
          int hh = h + dy, ww = w + dx;
          if ((unsigned)hh < 96u && (unsigned)ww < 96u) {
            float gk = gr[k];
            y += gk * bf2f(z[(size_t)(m + dy * 96 + dx) * 768 + bl * 256 + t]);
          }
        }
      }
    }
    yacc[(size_t)m * 256 + t] = y;
    if (bstart) { s += y; s2 += y * y; }
  }
  if (bstart) {
    atomicAdd(&stats[t], s);
    atomicAdd(&stats[256 + t], s2);
  }
}

// ---------- normalize + affine + transpose [m][co] -> [n][co][p] ----------
__global__ __launch_bounds__(256) void bn_apply(const float* __restrict__ yacc,
                                                const float* __restrict__ stats,
                                                const float* __restrict__ gamma,
                                                const float* __restrict__ beta,
                                                float* __restrict__ out) {
  __shared__ float tile[64][65];
  int t = threadIdx.x;
  int p0 = blockIdx.x * 64, co0 = blockIdx.y * 64, n = blockIdx.z;
  int cl = t & 63, q = t >> 6;
#pragma unroll
  for (int i = 0; i < 16; ++i) {
    int pr = q + i * 4;
    tile[pr][cl] = yacc[((size_t)n * HW + p0 + pr) * 256 + co0 + cl];
  }
  __syncthreads();
  const float inv_cnt = 1.f / 18432.f;
#pragma unroll
  for (int i = 0; i < 16; ++i) {
    int cr = q + i * 4;
    int c = co0 + cr;
    float mean = stats[c] * inv_cnt;
    float var = stats[256 + c] * inv_cnt - mean * mean;
    float sc = rsqrtf(var + 1e-5f) * gamma[c];
    float sh = beta[c] - mean * sc;
    out[(size_t)(n * 256 + c) * HW + p0 + cl] = tile[cl][cr] * sc + sh;
  }
}

extern "C" void kernel_launch(void* const* d_in, const int* in_sizes, int n_in,
                              void* d_out, int out_size, void* d_ws, size_t ws_size,
                              hipStream_t stream) {
  const float* x = (const float*)d_in[0];
  const float* Wc = (const float*)d_in[1];
  const float* Ws = (const float*)d_in[2];
  const float* gamma = (const float*)d_in[3];
  const float* beta = (const float*)d_in[4];
  float* out = (float*)d_out;

  unsigned short* xb = (unsigned short*)d_ws;      // 4718592 bf16
  unsigned short* Wsb = xb + 4718592;              // 393216 bf16
  unsigned short* Wcb = Wsb + 393216;              // 110592 bf16
  unsigned short* z = Wcb + 110592;                // 14155776 bf16 (18432 x 768)
  float* g45 = (float*)(z + 14155776);             // 884736 f32
  float* gsm = g45 + 884736;                       // 884736 f32
  float* yacc = gsm + 884736;                      // 4718592 f32
  float* stats = yacc + 4718592;                   // 512 f32   (total ~64.7 MB)

  hipMemsetAsync(stats, 0, 512 * sizeof(float), stream);
  xpose<<<dim3(144, 4, 2), 256, 0, stream>>>(x, xb);
  prep_w<<<1968, 256, 0, stream>>>(Ws, Wc, Wsb, Wcb);
  gemm_g<<<288, 256, 0, stream>>>(xb, Wcb, g45);
  softmax45<<<72, 256, 0, stream>>>(g45, gsm);
  for (int pass = 0; pass < 2; ++pass) {
    gemm_z<<<dim3(144, 6), 256, 0, stream>>>(xb, Wsb, z, pass * 768);
    accum<<<256, 256, 0, stream>>>(z, gsm, yacc, stats, pass * 3);
  }
  bn_apply<<<dim3(144, 4, 2), 256, 0, stream>>>(yacc, stats, gamma, beta, out);
}

// Round 3
// 265.150 us; speedup vs baseline: 2.5640x; 2.5028x over previous
//
#include <hip/hip_runtime.h>

typedef __bf16 bf16x8 __attribute__((ext_vector_type(8)));
typedef float f32x4 __attribute__((ext_vector_type(4)));

#define HW 9216
#define CCH 256

__device__ __forceinline__ unsigned short f2bf(float f) {
  unsigned u = __float_as_uint(f);
  unsigned r = (u + 0x7FFFu + ((u >> 16) & 1u)) >> 16;
  return (unsigned short)r;
}
__device__ __forceinline__ float bf2f(unsigned short h) {
  return __uint_as_float(((unsigned)h) << 16);
}

// y[0..8) += gk * unpack_bf16x8(v)
__device__ __forceinline__ void fma8(float* y, float gk, uint4 v) {
  const unsigned* u = (const unsigned*)&v;
#pragma unroll
  for (int i = 0; i < 4; ++i) {
    y[2 * i] += gk * __uint_as_float(u[i] << 16);
    y[2 * i + 1] += gk * __uint_as_float(u[i] & 0xFFFF0000u);
  }
}

// ---------- x [n][ci][p] fp32 -> xb [n*9216+p][ci] bf16 (LDS tile transpose) ----------
__global__ __launch_bounds__(256) void xpose(const float* __restrict__ x,
                                             unsigned short* __restrict__ xb) {
  __shared__ float tile[64][65];
  int t = threadIdx.x;
  int p0 = blockIdx.x * 64, ci0 = blockIdx.y * 64, n = blockIdx.z;
  int cl = t & 63, q = t >> 6;
#pragma unroll
  for (int i = 0; i < 16; ++i) {
    int cir = q + i * 4;
    tile[cir][cl] = x[((size_t)(n * 256 + ci0 + cir)) * HW + p0 + cl];
  }
  __syncthreads();
#pragma unroll
  for (int i = 0; i < 16; ++i) {
    int pr = q + i * 4;
    xb[((size_t)(n * HW + p0 + pr)) * 256 + ci0 + cl] = f2bf(tile[cl][pr]);
  }
}

// ---------- weight repack: Wsb[j=b*256+co][k=ci] bf16 ; Wcb[co48][k=j*256+ci] bf16 ----------
__global__ __launch_bounds__(256) void prep_w(const float* __restrict__ Ws,
                                              const float* __restrict__ Wc,
                                              unsigned short* __restrict__ Wsb,
                                              unsigned short* __restrict__ Wcb) {
  int u = blockIdx.x * 256 + threadIdx.x;
  if (u < 393216) {
    int j = u >> 8, k = u & 255;
    int co = j & 255, b = j >> 8;
    Wsb[u] = f2bf(Ws[(size_t)co * 1536 + b * 256 + k]);
  } else {
    int v = u - 393216;
    if (v < 110592) {
      int co = v / 2304, r = v % 2304;
      int j = r >> 8, ci = r & 255;
      Wcb[v] = (co < 45) ? f2bf(Wc[(size_t)co * 2304 + ci * 9 + j]) : (unsigned short)0;
    }
  }
}

// ---------- z[m][zc0..zc0+128) = xb . Wsb^T  (MFMA, 128x128 tile, BK=32) ----------
__global__ __launch_bounds__(256) void gemm_z(const unsigned short* __restrict__ xb,
                                              const unsigned short* __restrict__ Wsb,
                                              unsigned short* __restrict__ z, int jbase) {
  __shared__ unsigned short As[4 * 128 * 8];  // [q][mm][j]
  __shared__ unsigned short Bs[4 * 128 * 8];  // [q][nn][j]
  int t = threadIdx.x;
  int m0 = blockIdx.x * 128;
  int jr0 = jbase + blockIdx.y * 128;  // row in Wsb
  int zc0 = blockIdx.y * 128;          // col in z (768-wide local)
  int wid = t >> 6, lane = t & 63;
  int wm = (wid >> 1) * 64, wn = (wid & 1) * 64;
  int q = lane >> 4, ln = lane & 15;
  f32x4 acc[4][4] = {};

  for (int k0 = 0; k0 < 256; k0 += 32) {
#pragma unroll
    for (int r = 0; r < 2; ++r) {
      int idx = t + r * 256;
      int mm = idx >> 2, kq = idx & 3;
      ((uint4*)As)[kq * 128 + mm] =
          *(const uint4*)(xb + (size_t)(m0 + mm) * 256 + k0 + kq * 8);
      ((uint4*)Bs)[kq * 128 + mm] =
          *(const uint4*)(Wsb + (size_t)(jr0 + mm) * 256 + k0 + kq * 8);
    }
    __syncthreads();
    bf16x8 a[4], b[4];
#pragma unroll
    for (int f = 0; f < 4; ++f) {
      a[f] = ((const bf16x8*)As)[q * 128 + wm + f * 16 + ln];
      b[f] = ((const bf16x8*)Bs)[q * 128 + wn + f * 16 + ln];
    }
#pragma unroll
    for (int fm = 0; fm < 4; ++fm)
#pragma unroll
      for (int fn = 0; fn < 4; ++fn)
        acc[fm][fn] = __builtin_amdgcn_mfma_f32_16x16x32_bf16(a[fm], b[fn], acc[fm][fn], 0, 0, 0);
    __syncthreads();
  }

#pragma unroll
  for (int fm = 0; fm < 4; ++fm) {
    int mrow = m0 + wm + fm * 16 + q * 4;
#pragma unroll
    for (int fn = 0; fn < 4; ++fn) {
      int col = zc0 + wn + fn * 16 + ln;
#pragma unroll
      for (int r = 0; r < 4; ++r)
        z[(size_t)(mrow + r) * 768 + col] = f2bf(acc[fm][fn][r]);
    }
  }
}

// ---------- guidance: g45[m][48] = sum_j shift_j(xb) . Wcb^T  (K=2304, BM=64, BN=48) ----------
__global__ __launch_bounds__(256) void gemm_g(const unsigned short* __restrict__ xb,
                                              const unsigned short* __restrict__ Wcb,
                                              float* __restrict__ g45) {
  __shared__ unsigned short As[4 * 64 * 8];
  __shared__ unsigned short Bs[4 * 48 * 8];
  int t = threadIdx.x;
  int m0 = blockIdx.x * 64;
  int wid = t >> 6, lane = t & 63;
  int q = lane >> 4, ln = lane & 15;
  int mm = t >> 2, kq = t & 3;
  int m = m0 + mm;
  int nimg = m / HW, p = m % HW;
  int h = p / 96, w = p % 96;
  int mbase = nimg * HW;
  f32x4 acc[3] = {};

  for (int k0 = 0; k0 < 2304; k0 += 32) {
    int j = k0 >> 8;
    int dy = j / 3 - 1, dx = j % 3 - 1;
    int hh = h + dy, ww = w + dx;
    uint4 av = make_uint4(0, 0, 0, 0);
    if ((unsigned)hh < 96u && (unsigned)ww < 96u)
      av = *(const uint4*)(xb + (size_t)(mbase + hh * 96 + ww) * 256 + (k0 & 255) + kq * 8);
    ((uint4*)As)[kq * 64 + mm] = av;
    if (t < 192) {
      int nn = t >> 2, kq2 = t & 3;
      ((uint4*)Bs)[kq2 * 48 + nn] = *(const uint4*)(Wcb + (size_t)nn * 2304 + k0 + kq2 * 8);
    }
    __syncthreads();
    bf16x8 a = ((const bf16x8*)As)[q * 64 + wid * 16 + ln];
#pragma unroll
    for (int fn = 0; fn < 3; ++fn) {
      bf16x8 b = ((const bf16x8*)Bs)[q * 48 + fn * 16 + ln];
      acc[fn] = __builtin_amdgcn_mfma_f32_16x16x32_bf16(a, b, acc[fn], 0, 0, 0);
    }
    __syncthreads();
  }
#pragma unroll
  for (int fn = 0; fn < 3; ++fn) {
    int col = fn * 16 + ln;
    int mrow = m0 + wid * 16 + q * 4;
#pragma unroll
    for (int r = 0; r < 4; ++r)
      g45[(size_t)(mrow + r) * 48 + col] = acc[fn][r];
  }
}

// ---------- grouped softmax over 5 groups of 9 ----------
__global__ __launch_bounds__(256) void softmax45(const float* __restrict__ g45,
                                                 float* __restrict__ gsm) {
  int m = blockIdx.x * 256 + threadIdx.x;
  const float* g = g45 + (size_t)m * 48;
  float* o = gsm + (size_t)m * 48;
  for (int grp = 0; grp < 5; ++grp) {
    float v[9], mx = -1e30f;
#pragma unroll
    for (int k = 0; k < 9; ++k) { v[k] = g[grp * 9 + k]; mx = fmaxf(mx, v[k]); }
    float s = 0.f;
#pragma unroll
    for (int k = 0; k < 9; ++k) { v[k] = __expf(v[k] - mx); s += v[k]; }
    float inv = 1.f / s;
#pragma unroll
    for (int k = 0; k < 9; ++k) o[grp * 9 + k] = v[k] * inv;
  }
}

// ---------- branch accumulation (3 branches/pass), 8 rows x 32 threads/block ----------
// thread t: row = t>>5 (m = blk*8+row), channels (t&31)*8 .. +8 via uint4 bf16 loads.
// BN stats fused on final pass via LDS reduce + per-channel atomics.
__global__ __launch_bounds__(256) void accum(const unsigned short* __restrict__ z,
                                             const float* __restrict__ gsm,
                                             float* __restrict__ yacc,
                                             float* __restrict__ stats, int bstart) {
  __shared__ float s1[8][256];
  __shared__ float s2s[8][256];
  int t = threadIdx.x;
  int row = t >> 5, c32 = t & 31;
  int m = blockIdx.x * 8 + row;
  int p = m % HW;
  int h = p / 96, w = p % 96;
  const int dil[6] = {0, 1, 6, 12, 24, 36};
  float y[8];
  size_t ybase = (size_t)m * 256 + c32 * 8;

  if (bstart) {
    float4 y0 = *(const float4*)(yacc + ybase);
    float4 y1 = *(const float4*)(yacc + ybase + 4);
    y[0] = y0.x; y[1] = y0.y; y[2] = y0.z; y[3] = y0.w;
    y[4] = y1.x; y[5] = y1.y; y[6] = y1.z; y[7] = y1.w;
  } else {
#pragma unroll
    for (int j = 0; j < 8; ++j) y[j] = 0.f;
    // identity branch b=0 (z cols 0..256)
    fma8(y, 1.f, *(const uint4*)(z + (size_t)m * 768 + c32 * 8));
  }

#pragma unroll
  for (int bl = 0; bl < 3; ++bl) {
    int b = bstart + bl;
    if (b == 0) continue;
    int d = dil[b];
    const float* gr = gsm + (size_t)m * 48 + (b - 1) * 9;
#pragma unroll
    for (int k = 0; k < 9; ++k) {
      int dy = (k / 3 - 1) * d, dx = (k % 3 - 1) * d;
      int hh = h + dy, ww = w + dx;
      if ((unsigned)hh < 96u && (unsigned)ww < 96u) {
        float gk = gr[k];
        uint4 zv = *(const uint4*)(z + (size_t)(m + dy * 96 + dx) * 768 + bl * 256 + c32 * 8);
        fma8(y, gk, zv);
      }
    }
  }

  float4 o0 = make_float4(y[0], y[1], y[2], y[3]);
  float4 o1 = make_float4(y[4], y[5], y[6], y[7]);
  *(float4*)(yacc + ybase) = o0;
  *(float4*)(yacc + ybase + 4) = o1;

  if (bstart) {
#pragma unroll
    for (int j = 0; j < 8; ++j) {
      s1[row][c32 * 8 + j] = y[j];
      s2s[row][c32 * 8 + j] = y[j] * y[j];
    }
    __syncthreads();
    float a = 0.f, b2 = 0.f;
#pragma unroll
    for (int r = 0; r < 8; ++r) { a += s1[r][t]; b2 += s2s[r][t]; }
    atomicAdd(&stats[t], a);
    atomicAdd(&stats[256 + t], b2);
  }
}

// ---------- normalize + affine + transpose [m][co] -> [n][co][p] ----------
__global__ __launch_bounds__(256) void bn_apply(const float* __restrict__ yacc,
                                                const float* __restrict__ stats,
                                                const float* __restrict__ gamma,
                                                const float* __restrict__ beta,
                                                float* __restrict__ out) {
  __shared__ float tile[64][65];
  int t = threadIdx.x;
  int p0 = blockIdx.x * 64, co0 = blockIdx.y * 64, n = blockIdx.z;
  int cl = t & 63, q = t >> 6;
#pragma unroll
  for (int i = 0; i < 16; ++i) {
    int pr = q + i * 4;
    tile[pr][cl] = yacc[((size_t)n * HW + p0 + pr) * 256 + co0 + cl];
  }
  __syncthreads();
  const float inv_cnt = 1.f / 18432.f;
#pragma unroll
  for (int i = 0; i < 16; ++i) {
    int cr = q + i * 4;
    int c = co0 + cr;
    float mean = stats[c] * inv_cnt;
    float var = stats[256 + c] * inv_cnt - mean * mean;
    float sc = rsqrtf(var + 1e-5f) * gamma[c];
    float sh = beta[c] - mean * sc;
    out[(size_t)(n * 256 + c) * HW + p0 + cl] = tile[cl][cr] * sc + sh;
  }
}

extern "C" void kernel_launch(void* const* d_in, const int* in_sizes, int n_in,
                              void* d_out, int out_size, void* d_ws, size_t ws_size,
                              hipStream_t stream) {
  const float* x = (const float*)d_in[0];
  const float* Wc = (const float*)d_in[1];
  const float* Ws = (const float*)d_in[2];
  const float* gamma = (const float*)d_in[3];
  const float* beta = (const float*)d_in[4];
  float* out = (float*)d_out;

  unsigned short* xb = (unsigned short*)d_ws;      // 4718592 bf16
  unsigned short* Wsb = xb + 4718592;              // 393216 bf16
  unsigned short* Wcb = Wsb + 393216;              // 110592 bf16
  unsigned short* z = Wcb + 110592;                // 14155776 bf16 (18432 x 768)
  float* g45 = (float*)(z + 14155776);             // 884736 f32
  float* gsm = g45 + 884736;                       // 884736 f32
  float* yacc = gsm + 884736;                      // 4718592 f32
  float* stats = yacc + 4718592;                   // 512 f32   (total ~64.7 MB)

  hipMemsetAsync(stats, 0, 512 * sizeof(float), stream);
  xpose<<<dim3(144, 4, 2), 256, 0, stream>>>(x, xb);
  prep_w<<<1968, 256, 0, stream>>>(Ws, Wc, Wsb, Wcb);
  gemm_g<<<288, 256, 0, stream>>>(xb, Wcb, g45);
  softmax45<<<72, 256, 0, stream>>>(g45, gsm);
  for (int pass = 0; pass < 2; ++pass) {
    gemm_z<<<dim3(144, 6), 256, 0, stream>>>(xb, Wsb, z, pass * 768);
    accum<<<2304, 256, 0, stream>>>(z, gsm, yacc, stats, pass * 3);
  }
  bn_apply<<<dim3(144, 4, 2), 256, 0, stream>>>(yacc, stats, gamma, beta, out);
}

// Round 4
// 253.721 us; speedup vs baseline: 2.6795x; 1.0450x over previous
//
#include <hip/hip_runtime.h>

typedef __bf16 bf16x8 __attribute__((ext_vector_type(8)));
typedef float f32x4 __attribute__((ext_vector_type(4)));

#define HW 9216
#define CCH 256

__device__ __forceinline__ unsigned short f2bf(float f) {
  unsigned u = __float_as_uint(f);
  unsigned r = (u + 0x7FFFu + ((u >> 16) & 1u)) >> 16;
  return (unsigned short)r;
}

// y[0..8) += gk * unpack_bf16x8(v)
__device__ __forceinline__ void fma8(float* y, float gk, uint4 v) {
  const unsigned* u = (const unsigned*)&v;
#pragma unroll
  for (int i = 0; i < 4; ++i) {
    y[2 * i] += gk * __uint_as_float(u[i] << 16);
    y[2 * i + 1] += gk * __uint_as_float(u[i] & 0xFFFF0000u);
  }
}

// ---------- x [n][ci][p] fp32 -> xb [n*9216+p][ci] bf16 (LDS tile transpose) ----------
__global__ __launch_bounds__(256) void xpose(const float* __restrict__ x,
                                             unsigned short* __restrict__ xb) {
  __shared__ float tile[64][65];
  int t = threadIdx.x;
  int p0 = blockIdx.x * 64, ci0 = blockIdx.y * 64, n = blockIdx.z;
  int cl = t & 63, q = t >> 6;
#pragma unroll
  for (int i = 0; i < 16; ++i) {
    int cir = q + i * 4;
    tile[cir][cl] = x[((size_t)(n * 256 + ci0 + cir)) * HW + p0 + cl];
  }
  __syncthreads();
#pragma unroll
  for (int i = 0; i < 16; ++i) {
    int pr = q + i * 4;
    xb[((size_t)(n * HW + p0 + pr)) * 256 + ci0 + cl] = f2bf(tile[cl][pr]);
  }
}

// ---------- weight repack: Wsb[j=b*256+co][k=ci] bf16 ; Wcb[co48][k=j*256+ci] bf16 ----------
__global__ __launch_bounds__(256) void prep_w(const float* __restrict__ Ws,
                                              const float* __restrict__ Wc,
                                              unsigned short* __restrict__ Wsb,
                                              unsigned short* __restrict__ Wcb) {
  int u = blockIdx.x * 256 + threadIdx.x;
  if (u < 393216) {
    int j = u >> 8, k = u & 255;
    int co = j & 255, b = j >> 8;
    Wsb[u] = f2bf(Ws[(size_t)co * 1536 + b * 256 + k]);
  } else {
    int v = u - 393216;
    if (v < 110592) {
      int co = v / 2304, r = v % 2304;
      int j = r >> 8, ci = r & 255;
      Wcb[v] = (co < 45) ? f2bf(Wc[(size_t)co * 2304 + ci * 9 + j]) : (unsigned short)0;
    }
  }
}

// ---------- z[m][zc0..zc0+128) = xb . Wsb^T  (MFMA, 128x128 tile, BK=32) ----------
__global__ __launch_bounds__(256) void gemm_z(const unsigned short* __restrict__ xb,
                                              const unsigned short* __restrict__ Wsb,
                                              unsigned short* __restrict__ z, int jbase) {
  __shared__ unsigned short As[4 * 128 * 8];  // [q][mm][j]
  __shared__ unsigned short Bs[4 * 128 * 8];  // [q][nn][j]
  int t = threadIdx.x;
  int m0 = blockIdx.x * 128;
  int jr0 = jbase + blockIdx.y * 128;  // row in Wsb
  int zc0 = blockIdx.y * 128;          // col in z (768-wide local)
  int wid = t >> 6, lane = t & 63;
  int wm = (wid >> 1) * 64, wn = (wid & 1) * 64;
  int q = lane >> 4, ln = lane & 15;
  f32x4 acc[4][4] = {};

  for (int k0 = 0; k0 < 256; k0 += 32) {
#pragma unroll
    for (int r = 0; r < 2; ++r) {
      int idx = t + r * 256;
      int mm = idx >> 2, kq = idx & 3;
      ((uint4*)As)[kq * 128 + mm] =
          *(const uint4*)(xb + (size_t)(m0 + mm) * 256 + k0 + kq * 8);
      ((uint4*)Bs)[kq * 128 + mm] =
          *(const uint4*)(Wsb + (size_t)(jr0 + mm) * 256 + k0 + kq * 8);
    }
    __syncthreads();
    bf16x8 a[4], b[4];
#pragma unroll
    for (int f = 0; f < 4; ++f) {
      a[f] = ((const bf16x8*)As)[q * 128 + wm + f * 16 + ln];
      b[f] = ((const bf16x8*)Bs)[q * 128 + wn + f * 16 + ln];
    }
#pragma unroll
    for (int fm = 0; fm < 4; ++fm)
#pragma unroll
      for (int fn = 0; fn < 4; ++fn)
        acc[fm][fn] = __builtin_amdgcn_mfma_f32_16x16x32_bf16(a[fm], b[fn], acc[fm][fn], 0, 0, 0);
    __syncthreads();
  }

#pragma unroll
  for (int fm = 0; fm < 4; ++fm) {
    int mrow = m0 + wm + fm * 16 + q * 4;
#pragma unroll
    for (int fn = 0; fn < 4; ++fn) {
      int col = zc0 + wn + fn * 16 + ln;
#pragma unroll
      for (int r = 0; r < 4; ++r)
        z[(size_t)(mrow + r) * 768 + col] = f2bf(acc[fm][fn][r]);
    }
  }
}

// ---------- guidance: g45[m][48] = sum_j shift_j(xb) . Wcb^T  (K=2304, BM=64, BN=48) ----------
__global__ __launch_bounds__(256) void gemm_g(const unsigned short* __restrict__ xb,
                                              const unsigned short* __restrict__ Wcb,
                                              float* __restrict__ g45) {
  __shared__ unsigned short As[4 * 64 * 8];
  __shared__ unsigned short Bs[4 * 48 * 8];
  int t = threadIdx.x;
  int m0 = blockIdx.x * 64;
  int wid = t >> 6, lane = t & 63;
  int q = lane >> 4, ln = lane & 15;
  int mm = t >> 2, kq = t & 3;
  int m = m0 + mm;
  int nimg = m / HW, p = m % HW;
  int h = p / 96, w = p % 96;
  int mbase = nimg * HW;
  f32x4 acc[3] = {};

  for (int k0 = 0; k0 < 2304; k0 += 32) {
    int j = k0 >> 8;
    int dy = j / 3 - 1, dx = j % 3 - 1;
    int hh = h + dy, ww = w + dx;
    uint4 av = make_uint4(0, 0, 0, 0);
    if ((unsigned)hh < 96u && (unsigned)ww < 96u)
      av = *(const uint4*)(xb + (size_t)(mbase + hh * 96 + ww) * 256 + (k0 & 255) + kq * 8);
    ((uint4*)As)[kq * 64 + mm] = av;
    if (t < 192) {
      int nn = t >> 2, kq2 = t & 3;
      ((uint4*)Bs)[kq2 * 48 + nn] = *(const uint4*)(Wcb + (size_t)nn * 2304 + k0 + kq2 * 8);
    }
    __syncthreads();
    bf16x8 a = ((const bf16x8*)As)[q * 64 + wid * 16 + ln];
#pragma unroll
    for (int fn = 0; fn < 3; ++fn) {
      bf16x8 b = ((const bf16x8*)Bs)[q * 48 + fn * 16 + ln];
      acc[fn] = __builtin_amdgcn_mfma_f32_16x16x32_bf16(a, b, acc[fn], 0, 0, 0);
    }
    __syncthreads();
  }
#pragma unroll
  for (int fn = 0; fn < 3; ++fn) {
    int col = fn * 16 + ln;
    int mrow = m0 + wid * 16 + q * 4;
#pragma unroll
    for (int r = 0; r < 4; ++r)
      g45[(size_t)(mrow + r) * 48 + col] = acc[fn][r];
  }
}

// ---------- grouped softmax over 5 groups of 9 ----------
__global__ __launch_bounds__(256) void softmax45(const float* __restrict__ g45,
                                                 float* __restrict__ gsm) {
  int m = blockIdx.x * 256 + threadIdx.x;
  const float* g = g45 + (size_t)m * 48;
  float* o = gsm + (size_t)m * 48;
  for (int grp = 0; grp < 5; ++grp) {
    float v[9], mx = -1e30f;
#pragma unroll
    for (int k = 0; k < 9; ++k) { v[k] = g[grp * 9 + k]; mx = fmaxf(mx, v[k]); }
    float s = 0.f;
#pragma unroll
    for (int k = 0; k < 9; ++k) { v[k] = __expf(v[k] - mx); s += v[k]; }
    float inv = 1.f / s;
#pragma unroll
    for (int k = 0; k < 9; ++k) o[grp * 9 + k] = v[k] * inv;
  }
}

// ---------- branch accumulation, templated pass: all dilations compile-time ----------
// 8 rows x 32 threads/block; thread = 8 channels of one pixel (uint4 bf16).
// Per branch: batch-load 9 z-taps + 9 weights into registers, THEN fma -> ~10
// loads in flight per wave (round-3 version had VGPR=20 and ~2 in flight).
template <int PASS>
__global__ __launch_bounds__(256) void accum_k(const unsigned short* __restrict__ z,
                                               const float* __restrict__ gsm,
                                               float* __restrict__ yacc,
                                               float* __restrict__ stats) {
  __shared__ float red[8][256];
  int t = threadIdx.x;
  int row = t >> 5, c32 = t & 31;
  int m = blockIdx.x * 8 + row;
  int p = m % HW;
  int h = p / 96, w = p % 96;
  float y[8];
  size_t ybase = (size_t)m * 256 + c32 * 8;
  const unsigned short* zrow = z + (size_t)m * 768 + c32 * 8;

  if (PASS) {
    float4 y0 = *(const float4*)(yacc + ybase);
    float4 y1 = *(const float4*)(yacc + ybase + 4);
    y[0] = y0.x; y[1] = y0.y; y[2] = y0.z; y[3] = y0.w;
    y[4] = y1.x; y[5] = y1.y; y[6] = y1.z; y[7] = y1.w;
  } else {
#pragma unroll
    for (int j = 0; j < 8; ++j) y[j] = 0.f;
    fma8(y, 1.f, *(const uint4*)zrow);  // identity branch b=0, slice 0
  }

  // PASS 0: slices 1,2 hold d=1,6 ; PASS 1: slices 0,1,2 hold d=12,24,36
  const int nb = PASS ? 3 : 2;
#pragma unroll
  for (int bl = 0; bl < nb; ++bl) {
    const int d = PASS ? (bl == 0 ? 12 : (bl == 1 ? 24 : 36)) : (bl == 0 ? 1 : 6);
    const int slice = PASS ? bl : bl + 1;
    const int bidx = PASS ? bl + 3 : bl + 1;  // branch index 1..5
    const float* gr = gsm + (size_t)m * 48 + (bidx - 1) * 9;
    float gk[9];
    uint4 zv[9];
#pragma unroll
    for (int k = 0; k < 9; ++k) gk[k] = gr[k];
#pragma unroll
    for (int k = 0; k < 9; ++k) {
      const int DY = (k / 3 - 1) * d, DX = (k % 3 - 1) * d;
      uint4 v = make_uint4(0, 0, 0, 0);
      if ((unsigned)(h + DY) < 96u && (unsigned)(w + DX) < 96u)
        v = *(const uint4*)(zrow + (size_t)(DY * 96 + DX) * 768 + slice * 256);
      zv[k] = v;
    }
#pragma unroll
    for (int k = 0; k < 9; ++k) fma8(y, gk[k], zv[k]);
  }

  float4 o0 = make_float4(y[0], y[1], y[2], y[3]);
  float4 o1 = make_float4(y[4], y[5], y[6], y[7]);
  *(float4*)(yacc + ybase) = o0;
  *(float4*)(yacc + ybase + 4) = o1;

  if (PASS) {  // BN stats: per-channel sum & sumsq, one reused 8KB LDS buffer
#pragma unroll
    for (int j = 0; j < 8; ++j) red[row][c32 * 8 + j] = y[j];
    __syncthreads();
    float a = 0.f;
#pragma unroll
    for (int r = 0; r < 8; ++r) a += red[r][t];
    atomicAdd(&stats[t], a);
    __syncthreads();
#pragma unroll
    for (int j = 0; j < 8; ++j) red[row][c32 * 8 + j] = y[j] * y[j];
    __syncthreads();
    float b = 0.f;
#pragma unroll
    for (int r = 0; r < 8; ++r) b += red[r][t];
    atomicAdd(&stats[256 + t], b);
  }
}

// ---------- normalize + affine + transpose [m][co] -> [n][co][p] ----------
__global__ __launch_bounds__(256) void bn_apply(const float* __restrict__ yacc,
                                                const float* __restrict__ stats,
                                                const float* __restrict__ gamma,
                                                const float* __restrict__ beta,
                                                float* __restrict__ out) {
  __shared__ float tile[64][65];
  int t = threadIdx.x;
  int p0 = blockIdx.x * 64, co0 = blockIdx.y * 64, n = blockIdx.z;
  int cl = t & 63, q = t >> 6;
#pragma unroll
  for (int i = 0; i < 16; ++i) {
    int pr = q + i * 4;
    tile[pr][cl] = yacc[((size_t)n * HW + p0 + pr) * 256 + co0 + cl];
  }
  __syncthreads();
  const float inv_cnt = 1.f / 18432.f;
#pragma unroll
  for (int i = 0; i < 16; ++i) {
    int cr = q + i * 4;
    int c = co0 + cr;
    float mean = stats[c] * inv_cnt;
    float var = stats[256 + c] * inv_cnt - mean * mean;
    float sc = rsqrtf(var + 1e-5f) * gamma[c];
    float sh = beta[c] - mean * sc;
    out[(size_t)(n * 256 + c) * HW + p0 + cl] = tile[cl][cr] * sc + sh;
  }
}

extern "C" void kernel_launch(void* const* d_in, const int* in_sizes, int n_in,
                              void* d_out, int out_size, void* d_ws, size_t ws_size,
                              hipStream_t stream) {
  const float* x = (const float*)d_in[0];
  const float* Wc = (const float*)d_in[1];
  const float* Ws = (const float*)d_in[2];
  const float* gamma = (const float*)d_in[3];
  const float* beta = (const float*)d_in[4];
  float* out = (float*)d_out;

  unsigned short* xb = (unsigned short*)d_ws;      // 4718592 bf16
  unsigned short* Wsb = xb + 4718592;              // 393216 bf16
  unsigned short* Wcb = Wsb + 393216;              // 110592 bf16
  unsigned short* z = Wcb + 110592;                // 14155776 bf16 (18432 x 768)
  float* g45 = (float*)(z + 14155776);             // 884736 f32
  float* gsm = g45 + 884736;                       // 884736 f32
  float* yacc = gsm + 884736;                      // 4718592 f32
  float* stats = yacc + 4718592;                   // 512 f32   (total ~64.7 MB)

  hipMemsetAsync(stats, 0, 512 * sizeof(float), stream);
  xpose<<<dim3(144, 4, 2), 256, 0, stream>>>(x, xb);
  prep_w<<<1968, 256, 0, stream>>>(Ws, Wc, Wsb, Wcb);
  gemm_g<<<288, 256, 0, stream>>>(xb, Wcb, g45);
  softmax45<<<72, 256, 0, stream>>>(g45, gsm);

  gemm_z<<<dim3(144, 6), 256, 0, stream>>>(xb, Wsb, z, 0);
  accum_k<0><<<2304, 256, 0, stream>>>(z, gsm, yacc, stats);
  gemm_z<<<dim3(144, 6), 256, 0, stream>>>(xb, Wsb, z, 768);
  accum_k<1><<<2304, 256, 0, stream>>>(z, gsm, yacc, stats);

  bn_apply<<<dim3(144, 4, 2), 256, 0, stream>>>(yacc, stats, gamma, beta, out);
}